// Round 2
// baseline (121.030 us; speedup 1.0000x reference)
//
#include <hip/hip_runtime.h>
#include <math.h>

#define K_TOP   8
#define EPS_F   1e-8f
#define T_DIM   2048
#define H_DIM   1024
#define NHEADS  16

__global__ __launch_bounds__(256, 1) void ctma_topk_agg_kernel(
    const float* __restrict__ mlp,   // [B, T, H]
    const float* __restrict__ attn,  // [B, Hh, T, T]
    float* __restrict__ out)         // [B, T, H]
{
    const int tid = threadIdx.x;
    const int row = blockIdx.x;      // b*T + t
    const int b   = row >> 11;       // / 2048
    const int t   = row & (T_DIM - 1);

    // tiny LDS: per-wave reduce partials, double-buffered (1 barrier/round)
    __shared__ float s_pv[2][4];
    __shared__ int   s_pi[2][4];

    // ---------------- Phase 1: head-mean row -> REGISTERS ----------------
    const float4* attn4 = reinterpret_cast<const float4*>(
        attn + (size_t)b * NHEADS * T_DIM * T_DIM + (size_t)t * T_DIM);
    const size_t head_stride4 = (size_t)T_DIM * T_DIM / 4;

    float acc[8];
    #pragma unroll
    for (int j = 0; j < 8; ++j) acc[j] = 0.0f;

    #pragma unroll
    for (int h = 0; h < NHEADS; ++h) {
        float4 a = attn4[(size_t)h * head_stride4 + tid];
        float4 c = attn4[(size_t)h * head_stride4 + 256 + tid];
        acc[0] += a.x; acc[1] += a.y; acc[2] += a.z; acc[3] += a.w;
        acc[4] += c.x; acc[5] += c.y; acc[6] += c.z; acc[7] += c.w;
    }

    // each thread owns 8 elements of the mean row, in registers:
    //   indices 4*tid..4*tid+3  and  1024+4*tid..1024+4*tid+3 (ascending in j)
    const float inv16 = 1.0f / (float)NHEADS;
    float v[8];
    int   gidx[8];
    #pragma unroll
    for (int j = 0; j < 4; ++j) { v[j]     = acc[j]     * inv16; gidx[j]     = 4 * tid + j; }
    #pragma unroll
    for (int j = 0; j < 4; ++j) { v[4 + j] = acc[4 + j] * inv16; gidx[4 + j] = 1024 + 4 * tid + j; }

    // ---------------- Phase 2: iterative top-8, register-resident ----------------
    const int lane = tid & 63;
    const int wave = tid >> 6;

    float wv[K_TOP];   // uniform winner values (all threads compute identically)
    int   wi[K_TOP];   // uniform winner indices
    unsigned mask = 0; // per-thread: which of my 8 slots are already extracted

    #pragma unroll
    for (int k = 0; k < K_TOP; ++k) {
        // local scan: ascending gidx order, strict > keeps lowest index on ties
        float best = -INFINITY;
        int   bidx = 0x7fffffff;
        #pragma unroll
        for (int j = 0; j < 8; ++j) {
            const float val = ((mask >> j) & 1u) ? -INFINITY : v[j];
            if (val > best) { best = val; bidx = gidx[j]; }
        }
        // wave-level (64-lane) argmax reduce, lowest-index tie-break
        #pragma unroll
        for (int off = 32; off > 0; off >>= 1) {
            const float ov = __shfl_down(best, off);
            const int   oi = __shfl_down(bidx, off);
            if (ov > best || (ov == best && oi < bidx)) { best = ov; bidx = oi; }
        }
        if (lane == 0) { s_pv[k & 1][wave] = best; s_pi[k & 1][wave] = bidx; }
        __syncthreads();
        // all threads merge the 4 wave partials redundantly -> uniform winner
        float bv = s_pv[k & 1][0];
        int   bi = s_pi[k & 1][0];
        #pragma unroll
        for (int w = 1; w < 4; ++w) {
            const float ov = s_pv[k & 1][w];
            const int   oi = s_pi[k & 1][w];
            if (ov > bv || (ov == bv && oi < bi)) { bv = ov; bi = oi; }
        }
        wv[k] = bv;
        wi[k] = bi;
        // owner masks the extracted element
        #pragma unroll
        for (int j = 0; j < 8; ++j) if (gidx[j] == bi) mask |= (1u << j);
    }

    // ---------------- Phase 3: renormalize + gather-weighted sum ----------------
    float wsum = 0.0f;
    #pragma unroll
    for (int k = 0; k < K_TOP; ++k) wsum += wv[k];
    wsum = fmaxf(wsum, EPS_F);
    const float invs = 1.0f / wsum;

    const float4* mlp4 = reinterpret_cast<const float4*>(mlp)
                       + (size_t)b * T_DIM * (H_DIM / 4);
    float4 o = make_float4(0.f, 0.f, 0.f, 0.f);
    #pragma unroll
    for (int k = 0; k < K_TOP; ++k) {
        const float w = wv[k] * invs;
        const float4 m = mlp4[(size_t)wi[k] * (H_DIM / 4) + tid];
        o.x += w * m.x; o.y += w * m.y; o.z += w * m.z; o.w += w * m.w;
    }
    reinterpret_cast<float4*>(out)[(size_t)row * (H_DIM / 4) + tid] = o;
}

extern "C" void kernel_launch(void* const* d_in, const int* in_sizes, int n_in,
                              void* d_out, int out_size, void* d_ws, size_t ws_size,
                              hipStream_t stream) {
    const float* mlp  = (const float*)d_in[0];   // [B, T, H] fp32
    const float* attn = (const float*)d_in[1];   // [B, Hh, T, T] fp32
    float* out = (float*)d_out;                  // [B, T, H] fp32

    const int B = in_sizes[0] / (T_DIM * H_DIM); // = 2
    const int nblocks = B * T_DIM;               // 4096 rows

    ctma_topk_agg_kernel<<<nblocks, 256, 0, stream>>>(mlp, attn, out);
}

// Round 3
// 114.910 us; speedup vs baseline: 1.0533x; 1.0533x over previous
//
#include <hip/hip_runtime.h>
#include <math.h>

#define K_TOP   8
#define EPS_F   1e-8f
#define T_DIM   2048
#define H_DIM   1024
#define NHEADS  16

// One 64-lane wave per (b,t) row. 4 independent waves per block, no barriers,
// no LDS. Each lane owns 32 elements of the head-mean row:
//   slot s (0..31): element e = 256*(s>>2) + 4*lane + (s&3)
__global__ __launch_bounds__(256, 4) void ctma_wave_row_kernel(
    const float* __restrict__ mlp,   // [B, T, H]
    const float* __restrict__ attn,  // [B, Hh, T, T]
    float* __restrict__ out)         // [B, T, H]
{
    const int lane = threadIdx.x & 63;
    const int wv_id = threadIdx.x >> 6;
    const int row = blockIdx.x * 4 + wv_id;   // b*T + t
    const int b   = row >> 11;                // / 2048
    const int t   = row & (T_DIM - 1);

    // ---------------- Phase 1: head-mean row -> 32 registers/lane ----------------
    const float4* attn4 = reinterpret_cast<const float4*>(
        attn + (size_t)b * NHEADS * T_DIM * T_DIM + (size_t)t * T_DIM);
    const size_t hs4 = (size_t)T_DIM * T_DIM / 4;

    float acc[32];
    #pragma unroll
    for (int s = 0; s < 32; ++s) acc[s] = 0.0f;

    #pragma unroll 2
    for (int h = 0; h < NHEADS; ++h) {
        float4 tmp[8];
        #pragma unroll
        for (int j = 0; j < 8; ++j)
            tmp[j] = attn4[h * hs4 + (size_t)(lane + 64 * j)];
        #pragma unroll
        for (int j = 0; j < 8; ++j) {
            acc[4 * j + 0] += tmp[j].x;
            acc[4 * j + 1] += tmp[j].y;
            acc[4 * j + 2] += tmp[j].z;
            acc[4 * j + 3] += tmp[j].w;
        }
    }
    const float inv16 = 1.0f / (float)NHEADS;
    #pragma unroll
    for (int s = 0; s < 32; ++s) acc[s] *= inv16;

    // ---------------- Phase 2: iterative top-8, shuffle-only ----------------
    // element index of slot s for this lane
    //   e(s) = 256*(s>>2) + 4*lane + (s&3)   (ascending in s)
    // initial per-lane running argmax (lowest element index on ties -> strict >)
    float mybv = -INFINITY;
    int   mybi = 0x7fffffff;
    #pragma unroll
    for (int s = 0; s < 32; ++s) {
        if (acc[s] > mybv) { mybv = acc[s]; mybi = 256 * (s >> 2) + 4 * lane + (s & 3); }
    }
    unsigned mask = 0;   // extracted slots of this lane

    float wvv[K_TOP];    // uniform within wave
    int   wii[K_TOP];

    for (int k = 0; k < K_TOP; ++k) {
        float bv = mybv;
        int   bi = mybi;
        #pragma unroll
        for (int off = 32; off > 0; off >>= 1) {
            const float ov = __shfl_down(bv, off);
            const int   oi = __shfl_down(bi, off);
            if (ov > bv || (ov == bv && oi < bi)) { bv = ov; bi = oi; }
        }
        bv = __shfl(bv, 0);
        bi = __shfl(bi, 0);
        wvv[k] = bv;
        wii[k] = bi;
        // owning lane masks the slot and recomputes its running max
        if (lane == ((bi >> 2) & 63)) {
            mask |= 1u << (4 * (bi >> 8) + (bi & 3));
            mybv = -INFINITY;
            mybi = 0x7fffffff;
            #pragma unroll
            for (int s = 0; s < 32; ++s) {
                const float val = ((mask >> s) & 1u) ? -INFINITY : acc[s];
                if (val > mybv) { mybv = val; mybi = 256 * (s >> 2) + 4 * lane + (s & 3); }
            }
        }
    }

    // ---------------- Phase 3: renormalize + gather-weighted sum ----------------
    float wsum = 0.0f;
    #pragma unroll
    for (int k = 0; k < K_TOP; ++k) wsum += wvv[k];
    wsum = fmaxf(wsum, EPS_F);
    const float invs = 1.0f / wsum;

    const float4* mlp4 = reinterpret_cast<const float4*>(mlp)
                       + (size_t)b * T_DIM * (H_DIM / 4);
    float4 o[4];
    #pragma unroll
    for (int j = 0; j < 4; ++j) o[j] = make_float4(0.f, 0.f, 0.f, 0.f);

    #pragma unroll
    for (int k = 0; k < K_TOP; ++k) {
        const float w = wvv[k] * invs;
        const float4* src = mlp4 + (size_t)wii[k] * (H_DIM / 4);
        #pragma unroll
        for (int j = 0; j < 4; ++j) {
            const float4 m = src[lane + 64 * j];
            o[j].x += w * m.x; o[j].y += w * m.y; o[j].z += w * m.z; o[j].w += w * m.w;
        }
    }

    float4* out4 = reinterpret_cast<float4*>(out) + (size_t)row * (H_DIM / 4);
    #pragma unroll
    for (int j = 0; j < 4; ++j) out4[lane + 64 * j] = o[j];
}

extern "C" void kernel_launch(void* const* d_in, const int* in_sizes, int n_in,
                              void* d_out, int out_size, void* d_ws, size_t ws_size,
                              hipStream_t stream) {
    const float* mlp  = (const float*)d_in[0];   // [B, T, H] fp32
    const float* attn = (const float*)d_in[1];   // [B, Hh, T, T] fp32
    float* out = (float*)d_out;                  // [B, T, H] fp32

    const int B = in_sizes[0] / (T_DIM * H_DIM); // = 2
    const int rows = B * T_DIM;                  // 4096
    const int nblocks = rows / 4;                // 1024 blocks x 4 waves

    ctma_wave_row_kernel<<<nblocks, 256, 0, stream>>>(mlp, attn, out);
}